// Round 1
// baseline (401.741 us; speedup 1.0000x reference)
//
#include <hip/hip_runtime.h>

// MultiScaleSubsequenceExtractor: masked sliding-window means.
// B=128, L=1024, D=128, windows {4,8,16,32}; out rows/batch = 1021+1017+1009+993 = 4040.
// Memory-bound: ~265 MB write + ~67-100 MB read -> ~53-58 us floor at 6.3 TB/s.
// R2: non-temporal stores + NT staging loads. (kernel ~143 us; concurrency-bound, not BW-bound)
// R3: D-split blocks (half of D per block) -> LDS 50.4 KB -> 26 KB -> 3 -> 6 blocks/CU
//     (12 -> 24 waves/CU) to double memory-level parallelism. Staging loads revert to
//     cached + XCD-aware block swizzle so adjacent tiles' 32-row halos hit L2 instead of
//     HBM re-fetch. Stores remain non-temporal (keep the 265 MB output stream out of L2).

namespace {
constexpr int kB    = 128;
constexpr int kL    = 1024;
constexpr int kD    = 128;
constexpr int kD4   = kD / 4;        // float4 per full row = 32
constexpr int kDH4  = kD4 / 2;       // float4 per half row = 16
constexpr int TILE  = 64;            // output positions per block
constexpr int HALO  = 32;            // max window size
constexpr int ROWS  = TILE + HALO;   // 96 staged rows
constexpr int ROUT  = 4040;          // output rows per batch
constexpr int OFF4  = 0;
constexpr int OFF8  = 1021;
constexpr int OFF16 = 2038;          // 1021 + 1017
constexpr int OFF32 = 3047;          // 2038 + 1009
constexpr int NTILE = kL / TILE;     // 16 tiles along L
constexpr int NXCD  = 8;
constexpr int NBLK  = kB * 2 * NTILE;        // 4096 blocks (b, half, tile)
constexpr int CPX   = NBLK / NXCD;           // 512 logical blocks per XCD
}

typedef float v4f __attribute__((ext_vector_type(4)));

__device__ __forceinline__ void nt_store(float4* p, const float4& v) {
    v4f x;
    x.x = v.x; x.y = v.y; x.z = v.z; x.w = v.w;
    __builtin_nontemporal_store(x, reinterpret_cast<v4f*>(p));
}

__device__ __forceinline__ void acc4(float4& a, const float4& x) {
    a.x += x.x; a.y += x.y; a.z += x.z; a.w += x.w;
}
__device__ __forceinline__ void slide4(float4& a, const float4& xin, const float4& xout) {
    a.x += xin.x - xout.x; a.y += xin.y - xout.y;
    a.z += xin.z - xout.z; a.w += xin.w - xout.w;
}
__device__ __forceinline__ float4 scale4(const float4& v, float s) {
    return make_float4(v.x * s, v.y * s, v.z * s, v.w * s);
}

__global__ __launch_bounds__(256, 6)
void msse_kernel(const float* __restrict__ emb,
                 const int*   __restrict__ mask,
                 float*       __restrict__ out) {
    __shared__ float4 s_data[ROWS * kDH4];  // 24 KB: masked embeddings, half-D, row-major
    __shared__ float  s_mask[ROWS];
    __shared__ float  s_inv[4][TILE];       // 1/clip(count,1) per window per position

    // ---- XCD-aware swizzle: consecutive tiles of one (b, half) stay on one XCD ----
    // hw id h -> XCD h%8 (round-robin); logical id l so each XCD gets a contiguous
    // chunk of (b, half, tile) space, tile fastest => halo rows L2-resident.
    const int hid  = blockIdx.x;                         // 0..4095
    const int l    = (hid & (NXCD - 1)) * CPX + (hid >> 3);
    const int tile = l & (NTILE - 1);
    const int bh   = l >> 4;                             // (b*2 + half)
    const int b    = bh >> 1;
    const int half = bh & 1;
    const int i0   = tile * TILE;
    const int t    = threadIdx.x;

    // ---- stage masked input half-rows [i0, i0+96) into LDS, float4 coalesced (cached loads) ----
    const float4* gsrc = reinterpret_cast<const float4*>(emb)
                       + (size_t)b * kL * kD4 + half * kDH4;
    #pragma unroll
    for (int k = 0; k < (ROWS * kDH4) / 256; ++k) {   // 1536/256 = 6 iters
        const int f    = t + k * 256;
        const int row  = f >> 4;                      // 16 float4 per half-row
        const int grow = i0 + row;
        float4 v = make_float4(0.f, 0.f, 0.f, 0.f);
        float  m = 0.f;
        if (grow < kL) {
            m = (float)mask[b * kL + grow];
            v = gsrc[(size_t)grow * kD4 + (f & 15)];
            v.x *= m; v.y *= m; v.z *= m; v.w *= m;
        }
        s_data[f] = v;
        if ((f & 15) == 0) s_mask[row] = m;
    }
    __syncthreads();

    // ---- per-position window-count reciprocals (threads 0..63) ----
    if (t < TILE) {
        float c = 0.f, c4 = 0.f, c8 = 0.f, c16 = 0.f;
        #pragma unroll
        for (int j = 0; j < 32; ++j) {
            c += s_mask[t + j];
            if (j == 3)  c4  = c;
            if (j == 7)  c8  = c;
            if (j == 15) c16 = c;
        }
        s_inv[0][t] = 1.f / fmaxf(c4,  1.f);
        s_inv[1][t] = 1.f / fmaxf(c8,  1.f);
        s_inv[2][t] = 1.f / fmaxf(c16, 1.f);
        s_inv[3][t] = 1.f / fmaxf(c,   1.f);
    }
    __syncthreads();

    // ---- sliding-window sums: thread = (float4 column of 16, 4-position strip of 16) ----
    const int lane  = t & 15;        // float4 column within the half
    const int strip = t >> 4;        // 0..15
    const int base  = strip * 4;     // first local position of strip

    const float4* col = s_data + lane;   // row stride = kDH4

    float4 s4, s8, s16, s32;
    {
        float4 a  = make_float4(0.f, 0.f, 0.f, 0.f);
        float4 t4 = a, t8 = a, t16 = a;
        #pragma unroll
        for (int j = 0; j < 32; ++j) {
            acc4(a, col[(base + j) * kDH4]);
            if (j == 3)  t4  = a;
            if (j == 7)  t8  = a;
            if (j == 15) t16 = a;
        }
        s4 = t4; s8 = t8; s16 = t16; s32 = a;
    }

    float4* outb = reinterpret_cast<float4*>(out)
                 + (size_t)b * ROUT * kD4 + half * kDH4 + lane;

    #pragma unroll
    for (int p = 0; p < 4; ++p) {
        const int il = base + p;
        const int i  = i0 + il;

        if (i <= kL - 4)  nt_store(outb + (size_t)(OFF4  + i) * kD4, scale4(s4,  s_inv[0][il]));
        if (i <= kL - 8)  nt_store(outb + (size_t)(OFF8  + i) * kD4, scale4(s8,  s_inv[1][il]));
        if (i <= kL - 16) nt_store(outb + (size_t)(OFF16 + i) * kD4, scale4(s16, s_inv[2][il]));
        if (i <= kL - 32) nt_store(outb + (size_t)(OFF32 + i) * kD4, scale4(s32, s_inv[3][il]));

        // advance all windows to position i+1 (rows <= base+3+32 = 95, in range)
        const float4 x0 = col[(il)      * kDH4];
        const float4 xa = col[(il + 4)  * kDH4];
        const float4 xb = col[(il + 8)  * kDH4];
        const float4 xc = col[(il + 16) * kDH4];
        const float4 xd = col[(il + 32) * kDH4];
        slide4(s4,  xa, x0);
        slide4(s8,  xb, x0);
        slide4(s16, xc, x0);
        slide4(s32, xd, x0);
    }
}

extern "C" void kernel_launch(void* const* d_in, const int* in_sizes, int n_in,
                              void* d_out, int out_size, void* d_ws, size_t ws_size,
                              hipStream_t stream) {
    const float* emb  = (const float*)d_in[0];
    const int*   mask = (const int*)d_in[1];
    float*       out  = (float*)d_out;

    dim3 grid(NBLK);      // 4096 blocks = (128 b) x (2 D-halves) x (16 L-tiles)
    dim3 block(256);
    msse_kernel<<<grid, block, 0, stream>>>(emb, mask, out);
}

// Round 2
// 326.774 us; speedup vs baseline: 1.2294x; 1.2294x over previous
//
#include <hip/hip_runtime.h>

// MultiScaleSubsequenceExtractor: masked sliding-window means.
// B=128, L=1024, D=128, windows {4,8,16,32}; out rows/batch = 1021+1017+1009+993 = 4040.
// Memory-bound: ~265 MB write + ~65-100 MB read -> ~55 us floor at 6.3 TB/s.
// R2: NT stores + NT loads -> kernel ~145 us. rocprof (R3) revealed WRITE_SIZE = 487 MB
//     vs 265 MB ideal: NT stores bypass L2 write-combining, each 16B lane-store becomes
//     a ~32B EA request -> 1.84x write amplification + poor streaming rate.
// R3: D-split (6 blocks/CU): occupancy 57% but SLOWER (169 us) -> occupancy not the
//     limiter. Reverted.
// R4: R2 structure (full-D, TILE=64, 2048 blocks) with PLAIN cached stores (L2
//     write-combines the half-wave 512B-contiguous pattern into full lines) +
//     cached staging loads + XCD-aware swizzle (consecutive L-tiles of one batch on
//     one XCD -> 32-row halo L2-resident).

namespace {
constexpr int kB    = 128;
constexpr int kL    = 1024;
constexpr int kD    = 128;
constexpr int kD4   = kD / 4;        // float4 per row = 32
constexpr int TILE  = 64;            // output positions per block
constexpr int HALO  = 32;            // max window size
constexpr int ROWS  = TILE + HALO;   // 96 staged rows
constexpr int ROUT  = 4040;          // output rows per batch
constexpr int OFF4  = 0;
constexpr int OFF8  = 1021;
constexpr int OFF16 = 2038;          // 1021 + 1017
constexpr int OFF32 = 3047;          // 2038 + 1009
constexpr int NTILE = kL / TILE;     // 16 tiles along L
constexpr int NXCD  = 8;
constexpr int NBLK  = kB * NTILE;    // 2048 blocks (b, tile)
constexpr int CPX   = NBLK / NXCD;   // 256 logical blocks per XCD
}

__device__ __forceinline__ void acc4(float4& a, const float4& x) {
    a.x += x.x; a.y += x.y; a.z += x.z; a.w += x.w;
}
__device__ __forceinline__ void slide4(float4& a, const float4& xin, const float4& xout) {
    a.x += xin.x - xout.x; a.y += xin.y - xout.y;
    a.z += xin.z - xout.z; a.w += xin.w - xout.w;
}
__device__ __forceinline__ float4 scale4(const float4& v, float s) {
    return make_float4(v.x * s, v.y * s, v.z * s, v.w * s);
}

__global__ __launch_bounds__(256)
void msse_kernel(const float* __restrict__ emb,
                 const int*   __restrict__ mask,
                 float*       __restrict__ out) {
    __shared__ float4 s_data[ROWS * kD4];   // 48 KB: masked embeddings, row-major
    __shared__ float  s_mask[ROWS];
    __shared__ float  s_inv[4][TILE];       // 1/clip(count,1) per window per position

    // ---- XCD-aware swizzle: consecutive tiles of one batch stay on one XCD ----
    // hw id h -> XCD h%8 (round-robin). Logical id l gives each XCD a contiguous
    // chunk of (b, tile) space with tile fastest => 32-row halo is L2-resident.
    const int hid  = blockIdx.x;                       // 0..2047
    const int l    = (hid & (NXCD - 1)) * CPX + (hid >> 3);
    const int tile = l & (NTILE - 1);
    const int b    = l >> 4;                           // NTILE = 16
    const int i0   = tile * TILE;
    const int t    = threadIdx.x;

    // ---- stage masked input tile (rows [i0, i0+96)) into LDS, float4 coalesced ----
    const float4* gsrc = reinterpret_cast<const float4*>(emb) + (size_t)b * kL * kD4;
    #pragma unroll
    for (int k = 0; k < (ROWS * kD4) / 256; ++k) {   // 3072/256 = 12 iters
        const int f    = t + k * 256;
        const int row  = f >> 5;                     // 32 float4 per row
        const int grow = i0 + row;
        float4 v = make_float4(0.f, 0.f, 0.f, 0.f);
        float  m = 0.f;
        if (grow < kL) {
            m = (float)mask[b * kL + grow];
            v = gsrc[(size_t)grow * kD4 + (f & 31)];
            v.x *= m; v.y *= m; v.z *= m; v.w *= m;
        }
        s_data[f] = v;
        if ((f & 31) == 0) s_mask[row] = m;
    }
    __syncthreads();

    // ---- per-position window-count reciprocals (threads 0..63) ----
    if (t < TILE) {
        float c = 0.f, c4 = 0.f, c8 = 0.f, c16 = 0.f;
        #pragma unroll
        for (int j = 0; j < 32; ++j) {
            c += s_mask[t + j];
            if (j == 3)  c4  = c;
            if (j == 7)  c8  = c;
            if (j == 15) c16 = c;
        }
        s_inv[0][t] = 1.f / fmaxf(c4,  1.f);
        s_inv[1][t] = 1.f / fmaxf(c8,  1.f);
        s_inv[2][t] = 1.f / fmaxf(c16, 1.f);
        s_inv[3][t] = 1.f / fmaxf(c,   1.f);
    }
    __syncthreads();

    // ---- sliding-window sums: thread = (float4 column, 8-position strip) ----
    const int lane  = t & 31;        // float4 column index
    const int strip = t >> 5;        // 0..7
    const int base  = strip * 8;     // first local position of strip

    const float4* col = s_data + lane;   // row stride = kD4

    float4 s4, s8, s16, s32;
    {
        float4 a  = make_float4(0.f, 0.f, 0.f, 0.f);
        float4 t4 = a, t8 = a, t16 = a;
        #pragma unroll
        for (int j = 0; j < 32; ++j) {
            acc4(a, col[(base + j) * kD4]);
            if (j == 3)  t4  = a;
            if (j == 7)  t8  = a;
            if (j == 15) t16 = a;
        }
        s4 = t4; s8 = t8; s16 = t16; s32 = a;
    }

    float4* outb = reinterpret_cast<float4*>(out) + (size_t)b * ROUT * kD4 + lane;

    #pragma unroll
    for (int p = 0; p < 8; ++p) {
        const int il = base + p;
        const int i  = i0 + il;

        // plain cached stores: L2 write-combines half-wave 512B-contiguous chunks
        if (i <= kL - 4)  outb[(size_t)(OFF4  + i) * kD4] = scale4(s4,  s_inv[0][il]);
        if (i <= kL - 8)  outb[(size_t)(OFF8  + i) * kD4] = scale4(s8,  s_inv[1][il]);
        if (i <= kL - 16) outb[(size_t)(OFF16 + i) * kD4] = scale4(s16, s_inv[2][il]);
        if (i <= kL - 32) outb[(size_t)(OFF32 + i) * kD4] = scale4(s32, s_inv[3][il]);

        // advance all windows to position i+1 (max row = base+7+32 = 95, in range)
        const float4 x0 = col[(il)      * kD4];
        const float4 xa = col[(il + 4)  * kD4];
        const float4 xb = col[(il + 8)  * kD4];
        const float4 xc = col[(il + 16) * kD4];
        const float4 xd = col[(il + 32) * kD4];
        slide4(s4,  xa, x0);
        slide4(s8,  xb, x0);
        slide4(s16, xc, x0);
        slide4(s32, xd, x0);
    }
}

extern "C" void kernel_launch(void* const* d_in, const int* in_sizes, int n_in,
                              void* d_out, int out_size, void* d_ws, size_t ws_size,
                              hipStream_t stream) {
    const float* emb  = (const float*)d_in[0];
    const int*   mask = (const int*)d_in[1];
    float*       out  = (float*)d_out;

    dim3 grid(NBLK);      // 2048 blocks = (128 b) x (16 L-tiles), XCD-swizzled
    dim3 block(256);
    msse_kernel<<<grid, block, 0, stream>>>(emb, mask, out);
}